// Round 1
// baseline (319.886 us; speedup 1.0000x reference)
//
#include <hip/hip_runtime.h>
#include <hip/hip_bf16.h>
#include <math.h>

typedef __attribute__((ext_vector_type(8))) short short8x;
typedef __attribute__((ext_vector_type(4))) float f32x4;
typedef __attribute__((ext_vector_type(4))) unsigned short u16x4;

#define NSPLIT 8

__device__ __forceinline__ unsigned short f2bf(float x) {
  unsigned int u = __float_as_uint(x);
  u += 0x7fffu + ((u >> 16) & 1u);   // RNE
  return (unsigned short)(u >> 16);
}

__device__ __forceinline__ u16x4 cvt4(float4 v) {
  u16x4 r;
  r[0] = f2bf(v.x); r[1] = f2bf(v.y); r[2] = f2bf(v.z); r[3] = f2bf(v.w);
  return r;
}

// ---------------- K1: q_full[b][n] = dot(x[b][:], wq[n][:]), n in [0,24576) ----
__global__ __launch_bounds__(256) void k1_qproj(const float* __restrict__ x,
                                                const float* __restrict__ wq,
                                                float* __restrict__ qfull) {
  __shared__ float xs[16 * 512];
  const int tid = threadIdx.x;
  const int lane = tid & 63, wid = tid >> 6;
  const int row0 = blockIdx.x * 16 + wid * 4;
  float acc[4][16];
#pragma unroll
  for (int r = 0; r < 4; ++r)
#pragma unroll
    for (int bb = 0; bb < 16; ++bb) acc[r][bb] = 0.f;

  for (int kt = 0; kt < 3; ++kt) {
    __syncthreads();
    for (int u = tid; u < 2048; u += 256) {
      int bb = u >> 7, k4 = (u & 127) << 2;
      *(float4*)&xs[bb * 512 + k4] = *(const float4*)&x[bb * 1536 + kt * 512 + k4];
    }
    __syncthreads();
#pragma unroll
    for (int it = 0; it < 2; ++it) {
      const int ko = it * 256 + lane * 4;
      float4 wv[4];
#pragma unroll
      for (int r = 0; r < 4; ++r)
        wv[r] = *(const float4*)&wq[(size_t)(row0 + r) * 1536 + kt * 512 + ko];
#pragma unroll
      for (int bb = 0; bb < 16; ++bb) {
        float4 xv = *(const float4*)&xs[bb * 512 + ko];
#pragma unroll
        for (int r = 0; r < 4; ++r)
          acc[r][bb] += wv[r].x * xv.x + wv[r].y * xv.y + wv[r].z * xv.z + wv[r].w * xv.w;
      }
    }
  }
#pragma unroll
  for (int r = 0; r < 4; ++r)
#pragma unroll
    for (int bb = 0; bb < 16; ++bb) {
      float v = acc[r][bb];
#pragma unroll
      for (int mk = 1; mk < 64; mk <<= 1) v += __shfl_xor(v, mk, 64);
      acc[r][bb] = v;
    }
#pragma unroll
  for (int r = 0; r < 4; ++r) {
    const int row = row0 + r;
#pragma unroll
    for (int bb = 0; bb < 16; ++bb)
      if (lane == bb) qfull[bb * 24576 + row] = acc[r][bb];
  }
}

// ---------------- K2: rope q_pe (per b,h) and k_pe (per b) --------------------
__global__ void k2_rope(const float* __restrict__ qfull, const float* __restrict__ kpein,
                        const float* __restrict__ cosc, const float* __restrict__ sinc,
                        const int* __restrict__ sposp,
                        float* __restrict__ qper, float* __restrict__ kpen) {
  const int j = threadIdx.x;      // 0..31
  const int hh = blockIdx.x;      // 0..128 (128 == k_pe)
  const int b = blockIdx.y;
  const int pos = sposp[0];
  const float cj = cosc[pos * 64 + j];
  const float sj = sinc[pos * 64 + j];
  if (hh < 128) {
    const float* src = qfull + b * 24576 + hh * 192 + 128;
    float x0 = src[2 * j], x1 = src[2 * j + 1];
    float* dst = qper + (b * 128 + hh) * 64;
    dst[j] = x0 * cj - x1 * sj;
    dst[j + 32] = x1 * cj + x0 * sj;
  } else {
    const float* src = kpein + b * 64;
    float x0 = src[2 * j], x1 = src[2 * j + 1];
    float* dst = kpen + b * 64;
    dst[j] = x0 * cj - x1 * sj;
    dst[j + 32] = x1 * cj + x0 * sj;
  }
}

// ---------------- K3: q_abs[b][h][c] = sum_d q_full[b][h*192+d] * wkv[h][d][c] -
__global__ __launch_bounds__(256) void k3_absorb(const float* __restrict__ qfull,
                                                 const float* __restrict__ wkv,
                                                 float* __restrict__ qabs) {
  __shared__ float qs[16 * 128];
  const int tid = threadIdx.x;
  const int h = blockIdx.x;
  for (int u = tid; u < 2048; u += 256) {
    int bb = u >> 7, d = u & 127;
    qs[u] = qfull[bb * 24576 + h * 192 + d];
  }
  __syncthreads();
  const int c0 = tid, c1 = tid + 256;
  float acc0[16], acc1[16];
#pragma unroll
  for (int bb = 0; bb < 16; ++bb) { acc0[bb] = 0.f; acc1[bb] = 0.f; }
  const float* wbase = wkv + (size_t)h * 256 * 512;
  for (int d0 = 0; d0 < 128; d0 += 4) {
#pragma unroll
    for (int dd = 0; dd < 4; ++dd) {
      const float wa = wbase[(d0 + dd) * 512 + c0];
      const float wb = wbase[(d0 + dd) * 512 + c1];
#pragma unroll
      for (int bb = 0; bb < 16; ++bb) {
        const float qv = qs[bb * 128 + d0 + dd];
        acc0[bb] += qv * wa;
        acc1[bb] += qv * wb;
      }
    }
  }
#pragma unroll
  for (int bb = 0; bb < 16; ++bb) {
    qabs[(size_t)(bb * 128 + h) * 512 + c0] = acc0[bb];
    qabs[(size_t)(bb * 128 + h) * 512 + c1] = acc1[bb];
  }
}

// ---------------- K4: flash decode over KV splits (bf16 MFMA) -----------------
// grid (NSPLIT, 2, 16); block 256 = 4 waves x 16 heads
__global__ __launch_bounds__(256, 1) void k4_attn(
    const float* __restrict__ ckvc, const float* __restrict__ kpec,
    const float* __restrict__ ckvn, const float* __restrict__ qabs,
    const float* __restrict__ qper, const float* __restrict__ kpen,
    const int* __restrict__ sposp, int cap,
    float* __restrict__ opart, float* __restrict__ mlp) {
  // LDS: 158,208 B total
  __shared__ __align__(16) unsigned short q_sh[64 * 584];   // [h][k], k<576, pad->584
  __shared__ __align__(16) unsigned short kv_sh[32 * 584];  // [n][k]
  __shared__ __align__(16) unsigned short v2_sh[512 * 40];  // [c][n], n<32, pad->40
  __shared__ __align__(16) unsigned short p_sh[4 * 16 * 40];// [wave][h16][n], pad->40

  const int tid = threadIdx.x;
  const int split = blockIdx.x, hg = blockIdx.y, b = blockIdx.z;
  const int spos = sposp[0];
  const int kvlen = spos + 1;
  const int L = (kvlen + NSPLIT - 1) / NSPLIT;
  const int lo = split * L;
  const int hi = min(lo + L, kvlen);

  // stage Q (64 heads x 576) fp32 -> bf16
  for (int u = tid; u < 64 * 144; u += 256) {
    const int h = u / 144;
    const int c4 = (u - h * 144) * 4;
    const int hgl = b * 128 + hg * 64 + h;
    float4 v;
    if (c4 < 512) v = *(const float4*)(qabs + (size_t)hgl * 512 + c4);
    else          v = *(const float4*)(qper + (size_t)hgl * 64 + (c4 - 512));
    *(u16x4*)&q_sh[h * 584 + c4] = cvt4(v);
  }

  const int lane = tid & 63;
  const int wid = tid >> 6;
  const int l15 = lane & 15;
  const int lg = lane >> 4;

  f32x4 acc[32];
#pragma unroll
  for (int i = 0; i < 32; ++i) acc[i] = (f32x4){0.f, 0.f, 0.f, 0.f};
  float mold[4] = {-1e30f, -1e30f, -1e30f, -1e30f};
  float lsum[4] = {0.f, 0.f, 0.f, 0.f};

  const float C2 = (1.0f / sqrtf(192.0f)) * 1.4426950408889634f; // scale * log2(e)

  const int aBase = (wid * 16 + l15) * 584 + lg * 8;
  const int bB0 = l15 * 584 + lg * 8;
  const int bB1 = (16 + l15) * 584 + lg * 8;
  const int vBase = l15 * 40 + lg * 8;
  const int pWbase = wid * 640;
  const int pRbase = wid * 640 + l15 * 40 + lg * 8;

  const int nt = (hi - lo + 31) >> 5;
  for (int t = 0; t < nt; ++t) {
    const int n0g = lo + t * 32;
    // stage KV rows [n][576]
    for (int u = tid; u < 32 * 144; u += 256) {
      const int nrel = u / 144;
      const int c4 = (u - nrel * 144) * 4;
      const int n = n0g + nrel;
      float4 v = make_float4(0.f, 0.f, 0.f, 0.f);
      if (n < kvlen) {
        if (c4 < 512) {
          v = (n == spos) ? *(const float4*)(ckvn + (size_t)b * 512 + c4)
                          : *(const float4*)(ckvc + ((size_t)b * cap + n) * 512 + c4);
        } else {
          const int d = c4 - 512;
          v = (n == spos) ? *(const float4*)(kpen + (size_t)b * 64 + d)
                          : *(const float4*)(kpec + ((size_t)b * cap + n) * 64 + d);
        }
      }
      *(u16x4*)&kv_sh[nrel * 584 + c4] = cvt4(v);
    }
    // stage V transposed [c][n]
    for (int u = tid; u < 512 * 8; u += 256) {
      const int c = u & 511;
      const int n4 = (u >> 9) * 4;
      u16x4 w;
#pragma unroll
      for (int k = 0; k < 4; ++k) {
        const int n = n0g + n4 + k;
        float vv = 0.f;
        if (n < kvlen)
          vv = (n == spos) ? ckvn[(size_t)b * 512 + c] : ckvc[((size_t)b * cap + n) * 512 + c];
        w[k] = f2bf(vv);
      }
      *(u16x4*)&v2_sh[c * 40 + n4] = w;
    }
    __syncthreads();

    // scores: S[16h][32n] = Q(16x576) x KV(32x576)^T
    f32x4 D0 = (f32x4){0.f, 0.f, 0.f, 0.f};
    f32x4 D1 = (f32x4){0.f, 0.f, 0.f, 0.f};
#pragma unroll
    for (int s = 0; s < 18; ++s) {
      short8x a = *(const short8x*)&q_sh[aBase + s * 32];
      short8x fb0 = *(const short8x*)&kv_sh[bB0 + s * 32];
      short8x fb1 = *(const short8x*)&kv_sh[bB1 + s * 32];
      D0 = __builtin_amdgcn_mfma_f32_16x16x32_bf16(a, fb0, D0, 0, 0, 0);
      D1 = __builtin_amdgcn_mfma_f32_16x16x32_bf16(a, fb1, D1, 0, 0, 0);
    }

    const bool v0 = (n0g + l15) < hi;
    const bool v1 = (n0g + 16 + l15) < hi;
    float alpha[4];
#pragma unroll
    for (int r = 0; r < 4; ++r) {
      const float t0 = v0 ? D0[r] * C2 : -1e30f;
      const float t1 = v1 ? D1[r] * C2 : -1e30f;
      float mx = fmaxf(t0, t1);
      mx = fmaxf(mx, __shfl_xor(mx, 1, 64));
      mx = fmaxf(mx, __shfl_xor(mx, 2, 64));
      mx = fmaxf(mx, __shfl_xor(mx, 4, 64));
      mx = fmaxf(mx, __shfl_xor(mx, 8, 64));
      const float mn = fmaxf(mold[r], mx);
      alpha[r] = exp2f(mold[r] - mn);
      const float p0 = v0 ? exp2f(t0 - mn) : 0.f;
      const float p1 = v1 ? exp2f(t1 - mn) : 0.f;
      float rs = p0 + p1;
      rs += __shfl_xor(rs, 1, 64);
      rs += __shfl_xor(rs, 2, 64);
      rs += __shfl_xor(rs, 4, 64);
      rs += __shfl_xor(rs, 8, 64);
      lsum[r] = lsum[r] * alpha[r] + rs;
      mold[r] = mn;
      p_sh[pWbase + (lg * 4 + r) * 40 + l15] = f2bf(p0);
      p_sh[pWbase + (lg * 4 + r) * 40 + 16 + l15] = f2bf(p1);
    }
    const f32x4 av = {alpha[0], alpha[1], alpha[2], alpha[3]};
#pragma unroll
    for (int cg = 0; cg < 32; ++cg) acc[cg] *= av;

    __syncthreads();

    // PV: O[16h][512c] += P(16x32) x V(32x512)
    const short8x pa = *(const short8x*)&p_sh[pRbase];
#pragma unroll
    for (int cg = 0; cg < 32; ++cg) {
      short8x bv = *(const short8x*)&v2_sh[cg * 640 + vBase];
      acc[cg] = __builtin_amdgcn_mfma_f32_16x16x32_bf16(pa, bv, acc[cg], 0, 0, 0);
    }
    __syncthreads();
  }

  // epilogue: partials
  const int hb = b * 128 + hg * 64 + wid * 16 + lg * 4;
#pragma unroll
  for (int r = 0; r < 4; ++r) {
    const size_t ob = ((size_t)(hb + r) * NSPLIT + split) * 512;
#pragma unroll
    for (int cg = 0; cg < 32; ++cg)
      opart[ob + cg * 16 + l15] = acc[cg][r];
    if (l15 == 0) {
      mlp[(size_t)(hb + r) * 16 + split * 2] = mold[r];
      mlp[(size_t)(hb + r) * 16 + split * 2 + 1] = lsum[r];
    }
  }
}

// ---------------- K5: combine splits ------------------------------------------
__global__ __launch_bounds__(256) void k5_combine(const float* __restrict__ opart,
                                                  const float* __restrict__ mlp,
                                                  float* __restrict__ ofin) {
  const int gid = blockIdx.x * 256 + threadIdx.x;
  const int bh = gid >> 9, c = gid & 511;
  const float* m = mlp + bh * 16;
  float mi[NSPLIT], li[NSPLIT];
  float M = -1e30f;
#pragma unroll
  for (int i = 0; i < NSPLIT; ++i) {
    mi[i] = m[i * 2];
    li[i] = m[i * 2 + 1];
    M = fmaxf(M, mi[i]);
  }
  float Ls = 0.f, o = 0.f;
#pragma unroll
  for (int i = 0; i < NSPLIT; ++i) {
    const float w = exp2f(mi[i] - M);
    Ls += li[i] * w;
    o += w * opart[((size_t)bh * NSPLIT + i) * 512 + c];
  }
  ofin[gid] = o / Ls;
}

// ---------------- K6: out[b][h][d] = sum_c O[b][h][c] * wkv[h][128+d][c] -------
__global__ __launch_bounds__(256) void k6_proj(const float* __restrict__ ofin,
                                               const float* __restrict__ wkv,
                                               float* __restrict__ out) {
  __shared__ float os[16 * 512];
  const int tid = threadIdx.x;
  const int dh = blockIdx.x;  // 0..1
  const int h = blockIdx.y;   // 0..127
  for (int u = tid; u < 8192; u += 256) {
    int bb = u >> 9, c = u & 511;
    os[u] = ofin[(size_t)(bb * 128 + h) * 512 + c];
  }
  __syncthreads();
  const int q = tid >> 2, cq = tid & 3;
  const int d = dh * 64 + q;
  const float* wrow = wkv + ((size_t)(h * 256 + 128 + d)) * 512;
  float acc[16];
#pragma unroll
  for (int bb = 0; bb < 16; ++bb) acc[bb] = 0.f;
  for (int i = 0; i < 32; ++i) {
    const int c = cq * 4 + i * 16;
    const float4 w4 = *(const float4*)&wrow[c];
#pragma unroll
    for (int bb = 0; bb < 16; ++bb) {
      const float4 o4 = *(const float4*)&os[bb * 512 + c];
      acc[bb] += w4.x * o4.x + w4.y * o4.y + w4.z * o4.z + w4.w * o4.w;
    }
  }
#pragma unroll
  for (int bb = 0; bb < 16; ++bb) {
    float v = acc[bb];
    v += __shfl_xor(v, 1, 64);
    v += __shfl_xor(v, 2, 64);
    if (cq == 0) out[(size_t)(bb * 128 + h) * 128 + d] = v;
  }
}

extern "C" void kernel_launch(void* const* d_in, const int* in_sizes, int n_in,
                              void* d_out, int out_size, void* d_ws, size_t ws_size,
                              hipStream_t stream) {
  const float* x = (const float*)d_in[0];         // q_normed_dn (16,1,1536)
  const float* ckvn = (const float*)d_in[1];      // compressed_kv (16,1,512)
  const float* kpein = (const float*)d_in[2];     // k_pe (16,1,1,64)
  const int* sposp = (const int*)d_in[4];         // start_pos
  const float* ckvc = (const float*)d_in[5];      // ckv_cache (16,cap,512)
  const float* kpec = (const float*)d_in[6];      // k_pe_cache (16,cap,64)
  const float* sinc = (const float*)d_in[7];      // sin_cache (cap,64)
  const float* cosc = (const float*)d_in[8];      // cos_cache (cap,64)
  const float* wkv = (const float*)d_in[9];       // wkv_b (128,256,512)
  const float* wq = (const float*)d_in[10];       // wq_b (24576,1536)
  float* out = (float*)d_out;

  const int cap = in_sizes[5] / (16 * 512);

  float* ws = (float*)d_ws;
  float* qfull = ws;               // 393216
  float* qper = ws + 393216;       // 131072
  float* kpen = ws + 524288;       // 1024
  float* qabs = ws + 525312;       // 1048576
  float* opart = ws + 1573888;     // 8388608
  float* mlp = ws + 9962496;       // 32768
  float* ofin = ws + 9995264;      // 1048576  (total 11,043,840 floats = 44.2 MB)

  k1_qproj<<<dim3(1536), 256, 0, stream>>>(x, wq, qfull);
  k2_rope<<<dim3(129, 16), 32, 0, stream>>>(qfull, kpein, cosc, sinc, sposp, qper, kpen);
  k3_absorb<<<dim3(128), 256, 0, stream>>>(qfull, wkv, qabs);
  k4_attn<<<dim3(NSPLIT, 2, 16), 256, 0, stream>>>(ckvc, kpec, ckvn, qabs, qper, kpen,
                                                   sposp, cap, opart, mlp);
  k5_combine<<<dim3(4096), 256, 0, stream>>>(opart, mlp, ofin);
  k6_proj<<<dim3(2, 128), 256, 0, stream>>>(ofin, wkv, out);
}